// Round 7
// baseline (52.854 us; speedup 1.0000x reference)
//
#include <hip/hip_runtime.h>
#include <hip/hip_bf16.h>
#include <stdint.h>

#define IN_F 2048
#define OUT_F 128
#define KD 32
#define NR 256
#define OC 2176          // IN_F + OUT_F
#define OD 4096          // OUT_F * KD
#define KSPLIT 8
#define HSPLIT 8         // 32-k half-steps per split

typedef __bf16 bf16x8 __attribute__((ext_vector_type(8)));
typedef float  f32x4  __attribute__((ext_vector_type(4)));
typedef float  f32x16 __attribute__((ext_vector_type(16)));

// ---------------------------------------------------------------------------
// Prep (grid = 4096 + 256 blocks):
//  bid < 4096: Tb = bf16(T) in MFMA B-frag order: chunk c = kt*256 + ot;
//    lane l (fg=l>>4, fr=l&15) holds T[kt*32+fg*8+i][ot*16+fr] at Tb+(c*64+l)*8.
//  bid >= 4096: copy x -> out[:, 0:2048]; xb2 = bf16(x) in A-frag order.
// ---------------------------------------------------------------------------
__global__ __launch_bounds__(256) void prep_kernel(const float* __restrict__ x,
                                                   const float* __restrict__ Tm,
                                                   float* __restrict__ out,
                                                   __bf16* __restrict__ xb2,
                                                   __bf16* __restrict__ Tb) {
    const int bid = blockIdx.x;
    if (bid < 4096) {
        const int u     = bid * 256 + threadIdx.x;
        const int l     = u & 63;
        const int chunk = u >> 6;
        const int ot    = chunk & 255;
        const int kt    = chunk >> 8;
        const int fr = l & 15, fg = l >> 4;
        const float* src = Tm + (size_t)(kt * 32 + fg * 8) * OD + ot * 16 + fr;
        bf16x8 p;
        #pragma unroll
        for (int i = 0; i < 8; ++i) p[i] = (__bf16)src[(size_t)i * OD];
        *reinterpret_cast<bf16x8*>(Tb + (size_t)u * 8) = p;
    } else {
        const int q   = (bid - 4096) * 256 + threadIdx.x;
        const int row = q & 255;
        const int k0  = (q >> 8) << 3;
        const float* src = &x[row * IN_F + k0];
        float4 v0 = *reinterpret_cast<const float4*>(src);
        float4 v1 = *reinterpret_cast<const float4*>(src + 4);
        *reinterpret_cast<float4*>(&out[row * OC + k0])     = v0;
        *reinterpret_cast<float4*>(&out[row * OC + k0 + 4]) = v1;
        bf16x8 p = { (__bf16)v0.x, (__bf16)v0.y, (__bf16)v0.z, (__bf16)v0.w,
                     (__bf16)v1.x, (__bf16)v1.y, (__bf16)v1.z, (__bf16)v1.w };
        *reinterpret_cast<bf16x8*>(&xb2[(size_t)q * 8]) = p;
    }
}

// ---------------------------------------------------------------------------
// GEMM: P[ks][n][o] (f32, n-major partials) = sum_k x[n][k]*T[k][o].
// Barrier-free, LDS-free fragment stream. 256 thr = 4 waves; wave tile
// 32n x 64o; block 128n x 64o. grid (64 bo, 2 bn, 8 ks) = 1024 blocks
// -> 4 blocks/CU, 4 waves/SIMD. 3-deep rotating frag prefetch.
// ---------------------------------------------------------------------------
struct Frag { bf16x8 a0, a1, b0, b1, b2, b3; };

__device__ __forceinline__ Frag load_frag(const __bf16* __restrict__ xb2,
                                          const __bf16* __restrict__ Tb,
                                          int h, int n0, int c4, int lane) {
    const int fr = lane & 15, fg = lane >> 4;
    Frag f;
    const __bf16* ab = xb2 + ((size_t)(h * 4 + fg) * 256 + n0 + fr) * 8;
    f.a0 = *reinterpret_cast<const bf16x8*>(ab);
    f.a1 = *reinterpret_cast<const bf16x8*>(ab + 128);      // n0 + 16
    const __bf16* bb = Tb + ((size_t)(h * 256 + c4) * 64 + lane) * 8;
    f.b0 = *reinterpret_cast<const bf16x8*>(bb);
    f.b1 = *reinterpret_cast<const bf16x8*>(bb + 512);
    f.b2 = *reinterpret_cast<const bf16x8*>(bb + 1024);
    f.b3 = *reinterpret_cast<const bf16x8*>(bb + 1536);
    return f;
}

__device__ __forceinline__ void comp(const Frag& f, f32x4 acc[2][4]) {
    acc[0][0] = __builtin_amdgcn_mfma_f32_16x16x32_bf16(f.a0, f.b0, acc[0][0], 0, 0, 0);
    acc[1][0] = __builtin_amdgcn_mfma_f32_16x16x32_bf16(f.a1, f.b0, acc[1][0], 0, 0, 0);
    acc[0][1] = __builtin_amdgcn_mfma_f32_16x16x32_bf16(f.a0, f.b1, acc[0][1], 0, 0, 0);
    acc[1][1] = __builtin_amdgcn_mfma_f32_16x16x32_bf16(f.a1, f.b1, acc[1][1], 0, 0, 0);
    acc[0][2] = __builtin_amdgcn_mfma_f32_16x16x32_bf16(f.a0, f.b2, acc[0][2], 0, 0, 0);
    acc[1][2] = __builtin_amdgcn_mfma_f32_16x16x32_bf16(f.a1, f.b2, acc[1][2], 0, 0, 0);
    acc[0][3] = __builtin_amdgcn_mfma_f32_16x16x32_bf16(f.a0, f.b3, acc[0][3], 0, 0, 0);
    acc[1][3] = __builtin_amdgcn_mfma_f32_16x16x32_bf16(f.a1, f.b3, acc[1][3], 0, 0, 0);
}

__global__ __launch_bounds__(256, 4) void gemm_kernel(const __bf16* __restrict__ xb2,
                                                      const __bf16* __restrict__ Tb,
                                                      float* __restrict__ P) {
    const int tid  = threadIdx.x;
    const int lane = tid & 63;
    const int wid  = tid >> 6;
    const int fr   = lane & 15, fg = lane >> 4;
    const int c4   = blockIdx.x * 4;                 // 16-o chunk base (span 64 o)
    const int n0   = blockIdx.y * 128 + wid * 32;
    const int ks   = blockIdx.z;
    const int h0   = ks * HSPLIT;
    float* dst = P + ((size_t)ks << 20);             // 1M floats per partial

    f32x4 acc[2][4] = {};

    Frag s0 = load_frag(xb2, Tb, h0 + 0, n0, c4, lane);
    Frag s1 = load_frag(xb2, Tb, h0 + 1, n0, c4, lane);
    Frag s2 = load_frag(xb2, Tb, h0 + 2, n0, c4, lane);

    comp(s0, acc); s0 = load_frag(xb2, Tb, h0 + 3, n0, c4, lane);
    comp(s1, acc); s1 = load_frag(xb2, Tb, h0 + 4, n0, c4, lane);
    comp(s2, acc); s2 = load_frag(xb2, Tb, h0 + 5, n0, c4, lane);
    comp(s0, acc); s0 = load_frag(xb2, Tb, h0 + 6, n0, c4, lane);
    comp(s1, acc); s1 = load_frag(xb2, Tb, h0 + 7, n0, c4, lane);
    comp(s2, acc);
    comp(s0, acc);
    comp(s1, acc);

    // epilogue: D[row=n][col=o] -> dst[n*OD + o] (n-major)
    #pragma unroll
    for (int mi = 0; mi < 2; ++mi) {
        #pragma unroll
        for (int oi = 0; oi < 4; ++oi) {
            const int o  = (c4 + oi) * 16 + fr;
            const int nb = n0 + mi * 16 + fg * 4;
            #pragma unroll
            for (int r = 0; r < 4; ++r)
                dst[(size_t)(nb + r) * OD + o] = acc[mi][oi][r];
        }
    }
}

// ---------------------------------------------------------------------------
// Merge: Mn[n][o] = sum of 8 partials (all n-major, layout-preserving).
// grid 1024 x 256, f32x4 per thread, fully coalesced.
// ---------------------------------------------------------------------------
__global__ __launch_bounds__(256) void merge_kernel(const float* __restrict__ P,
                                                    float* __restrict__ Mn) {
    const size_t q = ((size_t)blockIdx.x * 256 + threadIdx.x) * 4;
    f32x4 v = *reinterpret_cast<const f32x4*>(P + q);
    #pragma unroll
    for (int s = 1; s < KSPLIT; ++s)
        v += *reinterpret_cast<const f32x4*>(P + ((size_t)s << 20) + q);
    *reinterpret_cast<f32x4*>(Mn + q) = v;
}

// ---------------------------------------------------------------------------
// Pairwise: o_b[j,f] = sum_i exp(-sum_d |M[i,f,d]-M[j,f,d]|).
// i-rows via SMEM (s_load_dwordx16 -> SGPRs, wave-shared, no 64-lane
// replication); j-rows per-lane in VGPRs. Pure-VALU inner loop:
// v_sub(s,v) + v_add(abs()) per element. grid (128 f, 4 jq), 256 thr;
// wave wid handles i in [wid*64, wid*64+64), 2 rows per batch.
// ---------------------------------------------------------------------------
__global__ __launch_bounds__(256, 2) void pairwise_kernel(const float* __restrict__ Mn,
                                                          float* __restrict__ out) {
    __shared__ float part[4][64];

    const int f    = blockIdx.x;
    const int jq   = blockIdx.y;
    const int tid  = threadIdx.x;
    const int lane = tid & 63;
    const int wid  = tid >> 6;

    const int j = jq * 64 + lane;
    f32x4 mj[8];
    const float* mjp = Mn + (size_t)j * OD + f * KD;
    #pragma unroll
    for (int p = 0; p < 8; ++p)
        mj[p] = *reinterpret_cast<const f32x4*>(mjp + p * 4);

    const int wid_u = __builtin_amdgcn_readfirstlane(wid);
    uint64_t addr = (uint64_t)(Mn + (size_t)(wid_u * 64) * OD + f * KD);

    float acc = 0.f;
    #pragma unroll 1
    for (int b = 0; b < 32; ++b) {
        f32x16 r0, r1, r2, r3;
        asm volatile(
            "s_load_dwordx16 %0, %4, 0\n\t"
            "s_load_dwordx16 %1, %4, 64\n\t"
            "s_load_dwordx16 %2, %4, 16384\n\t"
            "s_load_dwordx16 %3, %4, 16448\n\t"
            "s_waitcnt lgkmcnt(0)"
            : "=s"(r0), "=s"(r1), "=s"(r2), "=s"(r3)
            : "s"(addr));
        float nA = 0.f, nB = 0.f;
        #pragma unroll
        for (int d = 0; d < 16; ++d) {
            nA += fabsf(r0[d] - mj[d >> 2][d & 3]);
            nB += fabsf(r2[d] - mj[d >> 2][d & 3]);
        }
        #pragma unroll
        for (int d = 0; d < 16; ++d) {
            nA += fabsf(r1[d] - mj[4 + (d >> 2)][d & 3]);
            nB += fabsf(r3[d] - mj[4 + (d >> 2)][d & 3]);
        }
        acc += __expf(-nA) + __expf(-nB);
        addr += (uint64_t)2 * OD * sizeof(float);
    }

    part[wid][lane] = acc;
    __syncthreads();
    if (tid < 64) {
        float s = part[0][tid] + part[1][tid] + part[2][tid] + part[3][tid];
        out[(jq * 64 + tid) * OC + IN_F + f] = s;
    }
}

extern "C" void kernel_launch(void* const* d_in, const int* in_sizes, int n_in,
                              void* d_out, int out_size, void* d_ws, size_t ws_size,
                              hipStream_t stream) {
    const float* x  = (const float*)d_in[0];   // [256, 2048] f32
    const float* Tm = (const float*)d_in[1];   // [2048, 4096] f32
    float* out = (float*)d_out;                // [256, 2176] f32
    char*  ws  = (char*)d_ws;

    __bf16* xb2 = (__bf16*)ws;                      // 1 MB  A-frag image of x
    __bf16* Tb  = (__bf16*)(ws + (1u << 20));       // 16 MB B-frag image of T
    float*  P   = (float*)(ws + (17u << 20));       // 32 MB: 8 f32 n-major partials
    float*  Mn  = (float*)(ws + (49u << 20));       // 4 MB merged M, n-major

    prep_kernel<<<dim3(4096 + 256), 256, 0, stream>>>(x, Tm, out, xb2, Tb);
    gemm_kernel<<<dim3(64, 2, KSPLIT), 256, 0, stream>>>(xb2, Tb, P);
    merge_kernel<<<dim3(1024), 256, 0, stream>>>(P, Mn);
    pairwise_kernel<<<dim3(128, 4), 256, 0, stream>>>(Mn, out);
}